// Round 4
// baseline (228.868 us; speedup 1.0000x reference)
//
#include <hip/hip_runtime.h>
#include <math.h>

typedef unsigned int u32;
typedef unsigned long long u64;

#define BB 4
#define AA 262144              // 1<<18
#define NN (BB*AA)
#define PRE 4000
#define POST 1000
#define CAP 4096               // crow/nbox row stride
#define CAPR 5632              // key slots per batch: G [0,4000) + E [4000,5632)
#define MASKW 64
#define NBLK 63                // ceil(4000/64) mask word-blocks
#define NCHUNK 125             // 4000 / 32 exactly (reduce chunks)
#define SLICES 64              // private hist slices per batch (no atomics)
#define RSLICE 8               // rank j-slices (occupancy for k_rankp)
#define RWAVES 8               // k_reduce waves per batch (token-passing ring)
#define STOPVAL 0x7fffffff

// ---- workspace layout (bytes) ----  (R0 layout, col-major mask)
static const size_t OFF_CNTG = 0;                          // int, stride 32 ints x4
static const size_t OFF_CNTE = 512;                        // int, stride 32 ints x4
static const size_t OFF_KEYS = 1024;                       // u64[4][5632] = 176 KiB
static const size_t OFF_RANK = OFF_KEYS + (size_t)BB*CAPR*8;       // u32[4][5632]
static const size_t ZERO_END = OFF_RANK + (size_t)BB*CAPR*4;       // 271360
static const size_t OFF_HC   = ZERO_END;                   // u32[4][64][256] = 256 KiB
static const size_t OFF_HF   = OFF_HC + 262144;            // u32[4][64][256] = 256 KiB
static const size_t OFF_P1   = OFF_HF + 262144;            // u32[4] coarse bin C (pad)
static const size_t OFF_A1   = OFF_P1 + 128;               // u32[4] count above C
static const size_t OFF_P2   = OFF_A1 + 128;               // u32[4] 16-bit threshold
static const size_t OFF_CROW = OFF_P2 + 128;                       // float[4][4096][8]
static const size_t OFF_NBOX = OFF_CROW + (size_t)BB*CAP*8*4;
static const size_t OFF_MASK = OFF_NBOX + (size_t)BB*CAP*8*4;      // u64[4][64][4000] = 8 MB

// f32 sigmoid via correctly-rounded double exp (bit-exact, order == value order).
__device__ __forceinline__ u32 sigmoid_bits(float x) {
  float e = (float)exp(-(double)x);
  float s = 1.0f / (1.0f + e);
  return __float_as_uint(s);     // s in (0,1): bits > 0
}

// Monotone u32 transform of float bits (sigmoid monotone in x -> same order).
__device__ __forceinline__ u32 mono_bits(float x) {
  u32 f = __float_as_uint(x);
  return (f & 0x80000000u) ? ~f : (f | 0x80000000u);
}

// ---- coarse pass: 8-bit hist into PRIVATE per-block slices (no global atomics).
__global__ __launch_bounds__(256) void k_hcoarse(const float* __restrict__ obj,
                                                 u32* __restrict__ hc) {
  __shared__ u32 lh[256*16];
  int tid = threadIdx.x;
  for (int i = tid; i < 256*16; i += 256) lh[i] = 0;
  __syncthreads();
  size_t blockBase = (size_t)blockIdx.x * 4096;
  int rep = tid & 15;
  for (int k = 0; k < 16; ++k) {
    u32 tt = mono_bits(obj[blockBase + (size_t)k*256 + tid]);
    atomicAdd(&lh[(tt >> 24)*16 + rep], 1u);
  }
  __syncthreads();
  u32 s = 0;
  #pragma unroll
  for (int r = 0; r < 16; ++r) s += lh[tid*16 + r];
  hc[(size_t)blockIdx.x*256 + tid] = s;   // slice fully written, no memset needed
}

// ---- resolve1: per batch sum 64 slices, pick coarse bin C + count above ----
__global__ __launch_bounds__(256) void k_res1(const u32* __restrict__ hc,
                                              u32* __restrict__ C_out,
                                              u32* __restrict__ acc_out) {
  int b = blockIdx.x, t = threadIdx.x;
  __shared__ u32 sum[256];
  const u32* base = hc + (size_t)b*SLICES*256;
  u32 s = 0;
  for (int k = 0; k < SLICES; ++k) s += base[k*256 + t];
  sum[t] = s;
  __syncthreads();
  if (t == 0) {
    u32 acc = 0; int cs = 0;
    for (int i = 255; i >= 0; --i) {
      u32 c = sum[i];
      if (acc + c >= (u32)PRE) { cs = i; break; }
      acc += c;
    }
    C_out[b] = (u32)cs; acc_out[b] = acc;   // acc = count(coarse bin > C) <= 3999
  }
}

// ---- fine pass: hist bits[23:16] of elements whose coarse bin == C ----
__global__ __launch_bounds__(256) void k_hfine(const float* __restrict__ obj,
                                               const u32* __restrict__ C_in,
                                               u32* __restrict__ hf) {
  __shared__ u32 lh[256];
  int tid = threadIdx.x;
  lh[tid] = 0;
  __syncthreads();
  size_t blockBase = (size_t)blockIdx.x * 4096;
  int b = (int)(blockBase >> 18);
  u32 C = C_in[b];
  for (int k = 0; k < 16; ++k) {
    u32 tt = mono_bits(obj[blockBase + (size_t)k*256 + tid]);
    if ((tt >> 24) == C) atomicAdd(&lh[(tt >> 16) & 255u], 1u);
  }
  __syncthreads();
  hf[(size_t)blockIdx.x*256 + tid] = lh[tid];
}

// ---- resolve2: exact 16-bit threshold bin P = (C<<8)|fbin ----
__global__ __launch_bounds__(256) void k_res2(const u32* __restrict__ hf,
                                              const u32* __restrict__ C_in,
                                              const u32* __restrict__ acc_in,
                                              u32* __restrict__ P_out) {
  int b = blockIdx.x, t = threadIdx.x;
  __shared__ u32 sum[256];
  const u32* base = hf + (size_t)b*SLICES*256;
  u32 s = 0;
  for (int k = 0; k < SLICES; ++k) s += base[k*256 + t];
  sum[t] = s;
  __syncthreads();
  if (t == 0) {
    u32 acc = acc_in[b]; int fb = 0;
    for (int i = 255; i >= 0; --i) {
      u32 c = sum[i];
      if (acc + c >= (u32)PRE) { fb = i; break; }
      acc += c;
    }
    P_out[b] = (C_in[b] << 8) | (u32)fb;
  }
}

// ---- compact candidates (R8 semantics, passed) ----
// G (bin>P, provably <=3999) -> [0,4000); E (bins P-1,P) -> [4000,5632).
__global__ __launch_bounds__(256) void k_compact(const float* __restrict__ obj,
                                                 const u32* __restrict__ pfx,
                                                 int* __restrict__ cntG,
                                                 int* __restrict__ cntE,
                                                 u64* __restrict__ keys) {
  __shared__ u64 st[2048];            // G from front, E from back
  __shared__ int nG, nE, baseG, baseE;
  int tid = threadIdx.x;
  if (tid == 0) { nG = 0; nE = 0; }
  __syncthreads();
  size_t blockBase = (size_t)blockIdx.x * 4096;
  int b = (int)(blockBase >> 18);
  u32 P = pfx[b];
  for (int k = 0; k < 16; ++k) {
    size_t g = blockBase + (size_t)k*256 + tid;
    float x = obj[g];
    u32 tb = mono_bits(x) >> 16;
    if (tb + 1u >= P) {               // admit bins P-1, P, >P
      u32 m = sigmoid_bits(x);
      u64 key = ((u64)m << 32) | (u64)(AA - 1 - (u32)(g & (AA - 1)));
      if (tb > P) { int p = atomicAdd(&nG, 1); if (p < 1536) st[p] = key; }
      else        { int p = atomicAdd(&nE, 1); if (p < 512) st[2047 - p] = key; }
    }
  }
  __syncthreads();
  int ng = nG < 1536 ? nG : 1536;
  int ne = nE < 512 ? nE : 512;
  if (tid == 0) baseG = atomicAdd(&cntG[b*32], ng);
  if (tid == 1) baseE = atomicAdd(&cntE[b*32], ne);
  __syncthreads();
  for (int i = tid; i < ng; i += 256) {
    int p = baseG + i;
    if (p < 4000) keys[(size_t)b*CAPR + p] = st[i];          // G region [0,4000)
  }
  for (int i = tid; i < ne; i += 256) {
    int p = baseE + i;
    if (p < CAPR - 4000) keys[(size_t)b*CAPR + 4000 + p] = st[2047 - i]; // E region
  }
}

// ---- partial rank: sliced for occupancy (R10 win: ~11 waves/CU) ----
__global__ __launch_bounds__(64) void k_rankp(const u64* __restrict__ keys,
                                              u32* __restrict__ rank) {
  int b = blockIdx.z;
  int slot = blockIdx.x*64 + threadIdx.x;
  const u64* kb = keys + (size_t)b*CAPR;
  u64 myk = kb[slot];
  const ulonglong2* p2 = (const ulonglong2*)(kb + blockIdx.y*(CAPR/RSLICE));
  int r = 0;
  for (int base = 0; base < CAPR/(2*RSLICE); base += 16) {   // 22 batches of 16
    ulonglong2 v[16];
    #pragma unroll
    for (int k = 0; k < 16; ++k) v[k] = p2[base + k];
    #pragma unroll
    for (int k = 0; k < 16; ++k)
      r += (int)(v[k].x > myk) + (int)(v[k].y > myk);
  }
  if (r) atomicAdd(&rank[b*CAPR + slot], (u32)r);
}

// ---- decode top-4000 by final rank (data-parallel, full occupancy) ----
__global__ __launch_bounds__(256) void k_decode(const u64* __restrict__ keys,
                                                const u32* __restrict__ rank,
                                                const float* __restrict__ reg,
                                                const float* __restrict__ anc,
                                                float* __restrict__ crow,
                                                float* __restrict__ nbox) {
  int t = blockIdx.x*256 + threadIdx.x;        // over BB*CAPR
  int b = t / CAPR, slot = t - b*CAPR;
  u64 myk = keys[(size_t)b*CAPR + slot];
  int rk = (int)rank[b*CAPR + slot];
  if (myk == 0 || rk >= PRE) return;           // padding or beyond top-4000
  u32 m = (u32)(myk >> 32);
  int idx = AA - 1 - (int)(myk & 0xFFFFFFFFull);
  float score = __uint_as_float(m);
  size_t g = ((size_t)b << 18) + (size_t)idx;
  const float* rg = reg + g*7;
  const float* an = anc + g*7;
  float xa=an[0], ya=an[1], za=an[2], wa=an[3], la=an[4], ha=an[5], ra=an[6];
  float dx=rg[0], dy=rg[1], dz=rg[2], dw=rg[3], dl=rg[4], dh=rg[5], dr=rg[6];
  float diag = sqrtf(wa*wa + la*la);
  float x = dx*diag + xa;
  float y = dy*diag + ya;
  float z = dz*ha + za;
  float w = expf(dw)*wa;
  float l = expf(dl)*la;
  float h = expf(dh)*ha;
  float r = dr + ra;
  float* cr = crow + ((size_t)b*CAP + rk)*8;
  cr[0]=x; cr[1]=y; cr[2]=z; cr[3]=w; cr[4]=l; cr[5]=h; cr[6]=r; cr[7]=score;
  float sx = fmaxf(w, 0.2f), sy = fmaxf(l, 0.2f), sz = fmaxf(h, 0.2f);
  float* nb = nbox + ((size_t)b*CAP + rk)*8;
  nb[0]=x - sx*0.5f; nb[1]=y - sy*0.5f; nb[2]=z;
  nb[3]=x + sx*0.5f; nb[4]=y + sy*0.5f; nb[5]=z + sz;
  nb[6]=sx*sy*sz;   nb[7]=0.f;
}

// ---- suppression bitmask, col-major mask[b][word c][row i] (R0 layout) ----
__global__ __launch_bounds__(256) void k_mask(const float* __restrict__ nbox,
                                              u64* __restrict__ mask) {
  int c = blockIdx.x;            // word/column block 0..62
  int R = blockIdx.y;            // 256-row tile 0..15
  int b = blockIdx.z;
  if (c < R*4) return;           // tile fully below diagonal: words never read
  __shared__ float4 ca4[64], cb4[64];
  int t = threadIdx.x;
  int j0 = c*64;
  if (t < 64) {
    int j = j0 + t; int jc = j < PRE ? j : 0;
    const float4* p = (const float4*)(nbox + ((size_t)b*CAP + jc)*8);
    ca4[t] = p[0]; cb4[t] = p[1];
  }
  __syncthreads();
  int i = R*256 + t;
  if (i >= PRE) return;
  const float4* rp = (const float4*)(nbox + ((size_t)b*CAP + i)*8);
  float4 A = rp[0], Bv = rp[1];  // A = lo.xyz, hi.x ; Bv = hi.y, hi.z, vol, pad
  u64 bits = 0;
  #pragma unroll
  for (int jj = 0; jj < 64; ++jj) {
    float4 C = ca4[jj], D = cb4[jj];
    float d0 = fminf(A.w,  C.w) - fmaxf(A.x, C.x);
    float d1 = fminf(Bv.x, D.x) - fmaxf(A.y, C.y);
    float d2 = fminf(Bv.y, D.y) - fmaxf(A.z, C.z);
    float inter = fmaxf(d0, 0.f) * fmaxf(d1, 0.f) * fmaxf(d2, 0.f);
    float uni = Bv.z + D.z - inter;
    if (inter > 0.3f * uni) bits |= (1ull << jj);
  }
  int vcols = PRE - j0;                                  // >= 32 for c <= 62
  if (vcols < 64) bits &= ((1ull << vcols) - 1ull);      // clear cols >= PRE
  if (j0 <= i) {                                          // clear cols j <= i
    int d = i - j0;
    if (d >= 63) bits = 0;
    else bits &= ~((2ull << d) - 1ull);
  }
  mask[((size_t)b*MASKW + c)*PRE + i] = bits;
}

// ---- greedy NMS reduce: 8-wave TOKEN-PASSING ring ----
// R3 post-mortem: single-wave prefetch depth does NOT move the timed kernel
// (depth-2 and depth-4 both ~41us timed) -> the compiler's conservative waits
// put full load latency on every chunk regardless of depth. Fix: wave c%8
// owns chunk c with data preloaded in ITS OWN VGPRs a full rotation (>=8
// chunks, thousands of cycles) before its turn -- any vmcnt conservatism is
// absorbed in poll-idle time, never on the serial chain. State (removed[64],
// kc) passes wave->wave via LDS, acquire/release on a token `flag` (monotone;
// unique owner per value; STOPVAL broadcast at kc>=POST). Critical path =
// LDS handoff + ~300cy resolve per chunk.
__device__ __forceinline__ void load_chunk(u64 (&buf)[32], const u64* col,
                                           int c, int lane) {
  bool act = lane >= (c >> 1);           // words < row>>6 never written
  const ulonglong2* p = (const ulonglong2*)(col + c*32);
  #pragma unroll
  for (int k = 0; k < 16; ++k) {
    ulonglong2 v; v.x = 0; v.y = 0;
    if (act) v = p[k];
    buf[2*k] = v.x; buf[2*k+1] = v.y;
  }
}

__device__ __forceinline__ void resolve_chunk(u64 (&buf)[32], int c, int lane,
                                              u64& removed, int& kc,
                                              int* __restrict__ sel_lds) {
  int wq = c >> 1;
  int base = (c & 1) * 32;               // bit window of word wq for this chunk
  u64 cur = removed, km = 0;
  #pragma unroll
  for (int jj = 0; jj < 32; ++jj) {
    if (((cur >> (base + jj)) & 1ull) == 0ull) {
      km |= (1ull << (base + jj));
      cur |= buf[jj];
    }
  }
  u64 kmw = __shfl(km, wq, 64);          // only lane wq's km is meaningful
  #pragma unroll
  for (int jj = 0; jj < 32; ++jj) {
    if ((kmw >> (base + jj)) & 1ull) removed |= buf[jj];
  }
  int sh = base + (lane & 31);           // <= 63: no UB shift
  bool mine = (lane < 32) && ((kmw >> sh) & 1ull);
  int pos = kc + (int)__popcll(kmw & ((1ull << sh) - 1ull));
  if (mine && pos < POST) sel_lds[pos] = c*32 + lane;
  kc += (int)__popcll(kmw);              // uniform across wave
}

__global__ __launch_bounds__(RWAVES*64, 2) void k_reduce(const u64* __restrict__ mask,
                                                         const float* __restrict__ crow,
                                                         float* __restrict__ out) {
  __shared__ u64 rem_lds[64];
  __shared__ int sel_lds[POST];
  __shared__ int kc_lds;
  __shared__ int flag;           // # chunks resolved; STOPVAL when chain done
  int b = blockIdx.x;
  int tid = threadIdx.x;
  int w = tid >> 6;              // wave id 0..RWAVES-1
  int lane = tid & 63;
  const u64* col = mask + ((size_t)b*MASKW + lane)*PRE;   // this lane's word-column
  if (tid < 64) rem_lds[tid] = 0;
  if (tid == 0) { kc_lds = 0; flag = 0; }
  __syncthreads();

  u64 bufA[32], bufB[32];
  load_chunk(bufA, col, w, lane);            // chunks 0..7 issued at t=0
  load_chunk(bufB, col, w + RWAVES, lane);   // chunks 8..15 issued at t=0

  // turn(): wait for token==c, run resolve, pass token. true => chain done.
  auto turn = [&](u64 (&buf)[32], int c) -> bool {
    int v;
    for (;;) {
      v = __hip_atomic_load(&flag, __ATOMIC_ACQUIRE, __HIP_MEMORY_SCOPE_WORKGROUP);
      if (v >= c) break;         // v==c (my turn) or STOPVAL
      __builtin_amdgcn_s_sleep(1);
    }
    if (v != c) return true;     // STOPVAL
    __builtin_amdgcn_s_waitcnt(0);  // belt: drain lgkm before LDS state read
    u64 removed = rem_lds[lane];
    int kc = kc_lds;
    resolve_chunk(buf, c, lane, removed, kc, sel_lds);
    rem_lds[lane] = removed;
    if (lane == 0) kc_lds = kc;
    __threadfence_block();
    int nf = (kc >= POST || c + 1 >= NCHUNK) ? STOPVAL : c + 1;
    __hip_atomic_store(&flag, nf, __ATOMIC_RELEASE, __HIP_MEMORY_SCOPE_WORKGROUP);
    return nf == STOPVAL;
  };

  bool stop = false;
  int c = w;
  while (!stop) {
    stop = turn(bufA, c);                              // chunk c (bufA)
    if (!stop && c + 2*RWAVES < NCHUNK)
      load_chunk(bufA, col, c + 2*RWAVES, lane);       // refill, used 2 rotations on
    c += RWAVES;
    if (stop || c >= NCHUNK) break;
    stop = turn(bufB, c);                              // chunk c (bufB)
    if (!stop && c + 2*RWAVES < NCHUNK)
      load_chunk(bufB, col, c + 2*RWAVES, lane);
    c += RWAVES;
    if (c >= NCHUNK) break;
  }

  __syncthreads();
  int kc = kc_lds;
  int kcap = kc < POST ? kc : POST;
  for (int r = tid; r < POST; r += RWAVES*64) {
    float4 o0 = make_float4(0.f,0.f,0.f,0.f), o1 = o0;
    if (r < kcap) {
      int i = sel_lds[r];
      const float4* p = (const float4*)(crow + ((size_t)b*CAP + i)*8);
      o0 = p[0]; o1 = p[1];
    }
    float4* q = (float4*)(out + ((size_t)b*POST + r)*8);
    q[0] = o0; q[1] = o1;
  }
}

extern "C" void kernel_launch(void* const* d_in, const int* in_sizes, int n_in,
                              void* d_out, int out_size, void* d_ws, size_t ws_size,
                              hipStream_t stream) {
  const float* obj = (const float*)d_in[0];   // (N,)
  const float* reg = (const float*)d_in[1];   // (N,7)
  const float* anc = (const float*)d_in[2];   // (N,7)
  float* out = (float*)d_out;                 // (4,1000,8)
  char* ws = (char*)d_ws;

  int*  cntG = (int*)(ws + OFF_CNTG);
  int*  cntE = (int*)(ws + OFF_CNTE);
  u64*  keys = (u64*)(ws + OFF_KEYS);
  u32*  rank = (u32*)(ws + OFF_RANK);
  u32*  hc   = (u32*)(ws + OFF_HC);
  u32*  hf   = (u32*)(ws + OFF_HF);
  u32*  P1   = (u32*)(ws + OFF_P1);
  u32*  A1   = (u32*)(ws + OFF_A1);
  u32*  P2   = (u32*)(ws + OFF_P2);
  float* crow = (float*)(ws + OFF_CROW);
  float* nbox = (float*)(ws + OFF_NBOX);
  u64*  mask = (u64*)(ws + OFF_MASK);

  (void)hipMemsetAsync(ws, 0, ZERO_END, stream);   // counters + keys + rank

  k_hcoarse<<<NN/4096, 256, 0, stream>>>(obj, hc);
  k_res1<<<BB, 256, 0, stream>>>(hc, P1, A1);
  k_hfine<<<NN/4096, 256, 0, stream>>>(obj, P1, hf);
  k_res2<<<BB, 256, 0, stream>>>(hf, P1, A1, P2);
  k_compact<<<NN/4096, 256, 0, stream>>>(obj, P2, cntG, cntE, keys);
  k_rankp<<<dim3(CAPR/64, RSLICE, BB), 64, 0, stream>>>(keys, rank);
  k_decode<<<(BB*CAPR)/256, 256, 0, stream>>>(keys, rank, reg, anc, crow, nbox);
  k_mask<<<dim3(NBLK, 16, BB), 256, 0, stream>>>(nbox, mask);
  k_reduce<<<BB, RWAVES*64, 0, stream>>>(mask, crow, out);
}

// Round 5
// 218.050 us; speedup vs baseline: 1.0496x; 1.0496x over previous
//
#include <hip/hip_runtime.h>
#include <math.h>

typedef unsigned int u32;
typedef unsigned long long u64;

#define BB 4
#define AA 262144              // 1<<18
#define NN (BB*AA)
#define PRE 4000
#define POST 1000
#define CAP 4096               // crow/nbox row stride
#define CAPR 5632              // key slots per batch: G [0,4000) + E [4000,5632)
#define MASKW 64
#define NBLK 63                // ceil(4000/64) mask word-blocks
#define NCHUNK 125             // 4000 / 32 exactly (reduce chunks)
#define SLICES 64              // private hist slices per batch (no atomics)
#define RSLICE 8               // rank j-slices (occupancy for k_rankp)

// ---- workspace layout (bytes) ----  (col-major mask; R0 layout)
// [0, ZERO_END) zeroed by k_hcoarse's folded zero-pass (memset launch removed).
static const size_t OFF_CNTG = 0;                          // int, stride 32 ints x4
static const size_t OFF_CNTE = 512;                        // int, stride 32 ints x4
static const size_t OFF_KEYS = 1024;                       // u64[4][5632] = 176 KiB
static const size_t OFF_RANK = OFF_KEYS + (size_t)BB*CAPR*8;       // u32[4][5632]
static const size_t ZERO_END = OFF_RANK + (size_t)BB*CAPR*4;       // 271360
static const size_t OFF_HC   = ZERO_END;                   // u32[4][64][256] = 256 KiB
static const size_t OFF_HF   = OFF_HC + 262144;            // u32[4][64][256] = 256 KiB
static const size_t OFF_CROW = OFF_HF + 262144 + 384;              // float[4][4096][8]
static const size_t OFF_NBOX = OFF_CROW + (size_t)BB*CAP*8*4;
static const size_t OFF_MASK = OFF_NBOX + (size_t)BB*CAP*8*4;      // u64[4][64][4000] = 8 MB

// f32 sigmoid via correctly-rounded double exp (bit-exact, order == value order).
__device__ __forceinline__ u32 sigmoid_bits(float x) {
  float e = (float)exp(-(double)x);
  float s = 1.0f / (1.0f + e);
  return __float_as_uint(s);     // s in (0,1): bits > 0
}

// Monotone u32 transform of float bits (sigmoid monotone in x -> same order).
__device__ __forceinline__ u32 mono_bits(float x) {
  u32 f = __float_as_uint(x);
  return (f & 0x80000000u) ? ~f : (f | 0x80000000u);
}

// ---- coarse pass: 8-bit hist into PRIVATE per-block slices (no global atomics).
// R5: also zeroes [0, ZERO_END) (counters+keys+rank) -- replaces the memset
// launch. Safe: nothing reads that region before k_compact, two launches later.
__global__ __launch_bounds__(256) void k_hcoarse(const float* __restrict__ obj,
                                                 u32* __restrict__ hc,
                                                 u64* __restrict__ zws) {
  __shared__ u32 lh[256*16];
  int tid = threadIdx.x;
  for (int i = tid; i < 256*16; i += 256) lh[i] = 0;
  int zidx = blockIdx.x*256 + tid;
  if (zidx < (int)(ZERO_END/8)) zws[zidx] = 0;     // folded memset (33920 u64)
  __syncthreads();
  size_t blockBase = (size_t)blockIdx.x * 4096;
  int rep = tid & 15;
  for (int k = 0; k < 16; ++k) {
    u32 tt = mono_bits(obj[blockBase + (size_t)k*256 + tid]);
    atomicAdd(&lh[(tt >> 24)*16 + rep], 1u);
  }
  __syncthreads();
  u32 s = 0;
  #pragma unroll
  for (int r = 0; r < 16; ++r) s += lh[tid*16 + r];
  hc[(size_t)blockIdx.x*256 + tid] = s;   // slice fully written, no memset needed
}

// ---- fine pass (R5: res1 FOLDED IN) ----
// Every block re-derives C from hc: 64 wave-uniform 256-wide loads (L2
// broadcast) + the verbatim thread-0 scan. Deterministic integer math ->
// identical C in every block. Removes the k_res1 launch.
__global__ __launch_bounds__(256) void k_hfine(const float* __restrict__ obj,
                                               const u32* __restrict__ hc,
                                               u32* __restrict__ hf) {
  __shared__ u32 sum[256];
  __shared__ u32 lh[256];
  __shared__ u32 Cs;
  int tid = threadIdx.x;
  size_t blockBase = (size_t)blockIdx.x * 4096;
  int b = (int)(blockBase >> 18);
  {
    const u32* basep = hc + (size_t)b*SLICES*256;
    u32 s = 0;
    for (int k = 0; k < SLICES; ++k) s += basep[k*256 + tid];
    sum[tid] = s;
  }
  lh[tid] = 0;
  __syncthreads();
  if (tid == 0) {
    u32 acc = 0; int cs = 0;
    for (int i = 255; i >= 0; --i) {
      u32 c = sum[i];
      if (acc + c >= (u32)PRE) { cs = i; break; }
      acc += c;
    }
    Cs = (u32)cs;
  }
  __syncthreads();
  u32 C = Cs;
  for (int k = 0; k < 16; ++k) {
    u32 tt = mono_bits(obj[blockBase + (size_t)k*256 + tid]);
    if ((tt >> 24) == C) atomicAdd(&lh[(tt >> 16) & 255u], 1u);
  }
  __syncthreads();
  hf[(size_t)blockIdx.x*256 + tid] = lh[tid];
}

// ---- compact candidates (R5: res1+res2 FOLDED IN; R8 semantics preserved) ----
// Each block re-derives C, acc from hc, then P from hf (same verbatim scans).
// G (bin>P, provably <=3999) -> [0,4000); E (bins P-1,P) -> [4000,5632).
__global__ __launch_bounds__(256) void k_compact(const float* __restrict__ obj,
                                                 const u32* __restrict__ hc,
                                                 const u32* __restrict__ hf,
                                                 int* __restrict__ cntG,
                                                 int* __restrict__ cntE,
                                                 u64* __restrict__ keys) {
  __shared__ u32 sum[256];
  __shared__ u64 st[2048];            // G from front, E from back
  __shared__ int nG, nE, baseG, baseE;
  __shared__ u32 Cs, As, Ps;
  int tid = threadIdx.x;
  size_t blockBase = (size_t)blockIdx.x * 4096;
  int b = (int)(blockBase >> 18);
  // res1 re-derivation
  {
    const u32* basep = hc + (size_t)b*SLICES*256;
    u32 s = 0;
    for (int k = 0; k < SLICES; ++k) s += basep[k*256 + tid];
    sum[tid] = s;
  }
  if (tid == 0) { nG = 0; nE = 0; }
  __syncthreads();
  if (tid == 0) {
    u32 acc = 0; int cs = 0;
    for (int i = 255; i >= 0; --i) {
      u32 c = sum[i];
      if (acc + c >= (u32)PRE) { cs = i; break; }
      acc += c;
    }
    Cs = (u32)cs; As = acc;
  }
  __syncthreads();                     // tid0 done reading sum; Cs/As visible
  // res2 re-derivation (sum overwritten only after the sync above)
  {
    const u32* basep = hf + (size_t)b*SLICES*256;
    u32 s = 0;
    for (int k = 0; k < SLICES; ++k) s += basep[k*256 + tid];
    sum[tid] = s;
  }
  __syncthreads();
  if (tid == 0) {
    u32 acc = As; int fb = 0;
    for (int i = 255; i >= 0; --i) {
      u32 c = sum[i];
      if (acc + c >= (u32)PRE) { fb = i; break; }
      acc += c;
    }
    Ps = (Cs << 8) | (u32)fb;
  }
  __syncthreads();
  u32 P = Ps;
  // compact (unchanged, proven)
  for (int k = 0; k < 16; ++k) {
    size_t g = blockBase + (size_t)k*256 + tid;
    float x = obj[g];
    u32 tb = mono_bits(x) >> 16;
    if (tb + 1u >= P) {               // admit bins P-1, P, >P
      u32 m = sigmoid_bits(x);
      u64 key = ((u64)m << 32) | (u64)(AA - 1 - (u32)(g & (AA - 1)));
      if (tb > P) { int p = atomicAdd(&nG, 1); if (p < 1536) st[p] = key; }
      else        { int p = atomicAdd(&nE, 1); if (p < 512) st[2047 - p] = key; }
    }
  }
  __syncthreads();
  int ng = nG < 1536 ? nG : 1536;
  int ne = nE < 512 ? nE : 512;
  if (tid == 0) baseG = atomicAdd(&cntG[b*32], ng);
  if (tid == 1) baseE = atomicAdd(&cntE[b*32], ne);
  __syncthreads();
  for (int i = tid; i < ng; i += 256) {
    int p = baseG + i;
    if (p < 4000) keys[(size_t)b*CAPR + p] = st[i];          // G region [0,4000)
  }
  for (int i = tid; i < ne; i += 256) {
    int p = baseE + i;
    if (p < CAPR - 4000) keys[(size_t)b*CAPR + 4000 + p] = st[2047 - i]; // E region
  }
}

// ---- partial rank: sliced for occupancy (~11 waves/CU) ----
__global__ __launch_bounds__(64) void k_rankp(const u64* __restrict__ keys,
                                              u32* __restrict__ rank) {
  int b = blockIdx.z;
  int slot = blockIdx.x*64 + threadIdx.x;
  const u64* kb = keys + (size_t)b*CAPR;
  u64 myk = kb[slot];
  const ulonglong2* p2 = (const ulonglong2*)(kb + blockIdx.y*(CAPR/RSLICE));
  int r = 0;
  for (int base = 0; base < CAPR/(2*RSLICE); base += 16) {   // 22 batches of 16
    ulonglong2 v[16];
    #pragma unroll
    for (int k = 0; k < 16; ++k) v[k] = p2[base + k];
    #pragma unroll
    for (int k = 0; k < 16; ++k)
      r += (int)(v[k].x > myk) + (int)(v[k].y > myk);
  }
  if (r) atomicAdd(&rank[b*CAPR + slot], (u32)r);
}

// ---- decode top-4000 by final rank (data-parallel, full occupancy) ----
__global__ __launch_bounds__(256) void k_decode(const u64* __restrict__ keys,
                                                const u32* __restrict__ rank,
                                                const float* __restrict__ reg,
                                                const float* __restrict__ anc,
                                                float* __restrict__ crow,
                                                float* __restrict__ nbox) {
  int t = blockIdx.x*256 + threadIdx.x;        // over BB*CAPR
  int b = t / CAPR, slot = t - b*CAPR;
  u64 myk = keys[(size_t)b*CAPR + slot];
  int rk = (int)rank[b*CAPR + slot];
  if (myk == 0 || rk >= PRE) return;           // padding or beyond top-4000
  u32 m = (u32)(myk >> 32);
  int idx = AA - 1 - (int)(myk & 0xFFFFFFFFull);
  float score = __uint_as_float(m);
  size_t g = ((size_t)b << 18) + (size_t)idx;
  const float* rg = reg + g*7;
  const float* an = anc + g*7;
  float xa=an[0], ya=an[1], za=an[2], wa=an[3], la=an[4], ha=an[5], ra=an[6];
  float dx=rg[0], dy=rg[1], dz=rg[2], dw=rg[3], dl=rg[4], dh=rg[5], dr=rg[6];
  float diag = sqrtf(wa*wa + la*la);
  float x = dx*diag + xa;
  float y = dy*diag + ya;
  float z = dz*ha + za;
  float w = expf(dw)*wa;
  float l = expf(dl)*la;
  float h = expf(dh)*ha;
  float r = dr + ra;
  float* cr = crow + ((size_t)b*CAP + rk)*8;
  cr[0]=x; cr[1]=y; cr[2]=z; cr[3]=w; cr[4]=l; cr[5]=h; cr[6]=r; cr[7]=score;
  float sx = fmaxf(w, 0.2f), sy = fmaxf(l, 0.2f), sz = fmaxf(h, 0.2f);
  float* nb = nbox + ((size_t)b*CAP + rk)*8;
  nb[0]=x - sx*0.5f; nb[1]=y - sy*0.5f; nb[2]=z;
  nb[3]=x + sx*0.5f; nb[4]=y + sy*0.5f; nb[5]=z + sz;
  nb[6]=sx*sy*sz;   nb[7]=0.f;
}

// ---- suppression bitmask, col-major mask[b][word c][row i] (R0 layout) ----
__global__ __launch_bounds__(256) void k_mask(const float* __restrict__ nbox,
                                              u64* __restrict__ mask) {
  int c = blockIdx.x;            // word/column block 0..62
  int R = blockIdx.y;            // 256-row tile 0..15
  int b = blockIdx.z;
  if (c < R*4) return;           // tile fully below diagonal: words never read
  __shared__ float4 ca4[64], cb4[64];
  int t = threadIdx.x;
  int j0 = c*64;
  if (t < 64) {
    int j = j0 + t; int jc = j < PRE ? j : 0;
    const float4* p = (const float4*)(nbox + ((size_t)b*CAP + jc)*8);
    ca4[t] = p[0]; cb4[t] = p[1];
  }
  __syncthreads();
  int i = R*256 + t;
  if (i >= PRE) return;
  const float4* rp = (const float4*)(nbox + ((size_t)b*CAP + i)*8);
  float4 A = rp[0], Bv = rp[1];  // A = lo.xyz, hi.x ; Bv = hi.y, hi.z, vol, pad
  u64 bits = 0;
  #pragma unroll
  for (int jj = 0; jj < 64; ++jj) {
    float4 C = ca4[jj], D = cb4[jj];
    float d0 = fminf(A.w,  C.w) - fmaxf(A.x, C.x);
    float d1 = fminf(Bv.x, D.x) - fmaxf(A.y, C.y);
    float d2 = fminf(Bv.y, D.y) - fmaxf(A.z, C.z);
    float inter = fmaxf(d0, 0.f) * fmaxf(d1, 0.f) * fmaxf(d2, 0.f);
    float uni = Bv.z + D.z - inter;
    if (inter > 0.3f * uni) bits |= (1ull << jj);
  }
  int vcols = PRE - j0;                                  // >= 32 for c <= 62
  if (vcols < 64) bits &= ((1ull << vcols) - 1ull);      // clear cols >= PRE
  if (j0 <= i) {                                          // clear cols j <= i
    int d = i - j0;
    if (d >= 63) bits = 0;
    else bits &= ~((2ull << d) - 1ull);
  }
  mask[((size_t)b*MASKW + c)*PRE + i] = bits;
}

// ---- greedy NMS reduce, 32-row chunked DOUBLE-BUFFER (R0 exact) ----
// R0-R4 conclusion: profiled k_reduce times are cache-flush artifacts (cold
// HBM ~2400cy/chunk); in the timed graph-replay the mask is L2/LLC-hot and
// this kernel runs ~12-18us. Depth-4 (R3) and 8-wave ring (R4) moved the
// timed total <= +-8us -> keep the simplest proven structure.
__device__ __forceinline__ void load_chunk(u64 (&buf)[32], const u64* col,
                                           int c, int lane) {
  bool act = lane >= (c >> 1);           // words < row>>6 never written
  const ulonglong2* p = (const ulonglong2*)(col + c*32);
  #pragma unroll
  for (int k = 0; k < 16; ++k) {
    ulonglong2 v; v.x = 0; v.y = 0;
    if (act) v = p[k];
    buf[2*k] = v.x; buf[2*k+1] = v.y;
  }
}

__device__ __forceinline__ void resolve_chunk(u64 (&buf)[32], int c, int lane,
                                              u64& removed, int& kc,
                                              int* __restrict__ sel_lds) {
  int wq = c >> 1;
  int base = (c & 1) * 32;               // bit window of word wq for this chunk
  u64 cur = removed, km = 0;
  #pragma unroll
  for (int jj = 0; jj < 32; ++jj) {
    if (((cur >> (base + jj)) & 1ull) == 0ull) {
      km |= (1ull << (base + jj));
      cur |= buf[jj];
    }
  }
  u64 kmw = __shfl(km, wq, 64);          // only lane wq's km is meaningful
  #pragma unroll
  for (int jj = 0; jj < 32; ++jj) {
    if ((kmw >> (base + jj)) & 1ull) removed |= buf[jj];
  }
  int sh = base + (lane & 31);           // <= 63: no UB shift
  bool mine = (lane < 32) && ((kmw >> sh) & 1ull);
  int pos = kc + (int)__popcll(kmw & ((1ull << sh) - 1ull));
  if (mine && pos < POST) sel_lds[pos] = c*32 + lane;
  kc += (int)__popcll(kmw);              // uniform across wave
}

__global__ __launch_bounds__(64) void k_reduce(const u64* __restrict__ mask,
                                               const float* __restrict__ crow,
                                               float* __restrict__ out) {
  __shared__ int sel_lds[POST];
  int b = blockIdx.x, lane = threadIdx.x;
  const u64* col = mask + ((size_t)b*MASKW + lane)*PRE;   // this lane's word-column
  u64 bufA[32], bufB[32];
  u64 removed = 0;
  int kc = 0;
  load_chunk(bufA, col, 0, lane);
  for (int c = 0; c < NCHUNK; c += 2) {
    if (c + 1 < NCHUNK) load_chunk(bufB, col, c + 1, lane);   // prefetch
    resolve_chunk(bufA, c, lane, removed, kc, sel_lds);
    if (kc >= POST) break;
    if (c + 1 >= NCHUNK) break;
    if (c + 2 < NCHUNK) load_chunk(bufA, col, c + 2, lane);   // prefetch
    resolve_chunk(bufB, c + 1, lane, removed, kc, sel_lds);
    if (kc >= POST) break;
  }
  __syncthreads();
  int kcap = kc < POST ? kc : POST;
  for (int r = lane; r < POST; r += 64) {
    float4 o0 = make_float4(0.f,0.f,0.f,0.f), o1 = o0;
    if (r < kcap) {
      int i = sel_lds[r];
      const float4* p = (const float4*)(crow + ((size_t)b*CAP + i)*8);
      o0 = p[0]; o1 = p[1];
    }
    float4* q = (float4*)(out + ((size_t)b*POST + r)*8);
    q[0] = o0; q[1] = o1;
  }
}

extern "C" void kernel_launch(void* const* d_in, const int* in_sizes, int n_in,
                              void* d_out, int out_size, void* d_ws, size_t ws_size,
                              hipStream_t stream) {
  const float* obj = (const float*)d_in[0];   // (N,)
  const float* reg = (const float*)d_in[1];   // (N,7)
  const float* anc = (const float*)d_in[2];   // (N,7)
  float* out = (float*)d_out;                 // (4,1000,8)
  char* ws = (char*)d_ws;

  int*  cntG = (int*)(ws + OFF_CNTG);
  int*  cntE = (int*)(ws + OFF_CNTE);
  u64*  keys = (u64*)(ws + OFF_KEYS);
  u32*  rank = (u32*)(ws + OFF_RANK);
  u32*  hc   = (u32*)(ws + OFF_HC);
  u32*  hf   = (u32*)(ws + OFF_HF);
  float* crow = (float*)(ws + OFF_CROW);
  float* nbox = (float*)(ws + OFF_NBOX);
  u64*  mask = (u64*)(ws + OFF_MASK);

  // R5: 7 launches (was 10) -- memset folded into k_hcoarse, res1 into
  // k_hfine, res2 into k_compact. Theory: ~10us/launch inter-dispatch
  // overhead dominates the timed pipeline (kernel bodies sum to ~60us).
  k_hcoarse<<<NN/4096, 256, 0, stream>>>(obj, hc, (u64*)ws);
  k_hfine<<<NN/4096, 256, 0, stream>>>(obj, hc, hf);
  k_compact<<<NN/4096, 256, 0, stream>>>(obj, hc, hf, cntG, cntE, keys);
  k_rankp<<<dim3(CAPR/64, RSLICE, BB), 64, 0, stream>>>(keys, rank);
  k_decode<<<(BB*CAPR)/256, 256, 0, stream>>>(keys, rank, reg, anc, crow, nbox);
  k_mask<<<dim3(NBLK, 16, BB), 256, 0, stream>>>(nbox, mask);
  k_reduce<<<BB, 64, 0, stream>>>(mask, crow, out);
}